// Round 4
// baseline (3621.496 us; speedup 1.0000x reference)
//
#include <hip/hip_runtime.h>
#include <hip/hip_bf16.h>

#define NN     10000
#define NE     320000
#define H1DIM  200
#define NPAD   256
#define NCLS   8
#define NTST   2000
#define KDIM   10000
#define KPAD   10016
#define KSPL   4
#define KSTEPS 78   /* 78*32*4 = 9984, +16 tail on split 3 */

typedef __bf16 bf16x8 __attribute__((ext_vector_type(8)));
typedef float  f32x4  __attribute__((ext_vector_type(4)));

__device__ __forceinline__ void load_lds16(const void* g, void* l) {
  __builtin_amdgcn_global_load_lds(
      (__attribute__((address_space(1))) void*)(void*)g,
      (__attribute__((address_space(3))) void*)l, 16, 0, 0);
}

/* ---------------- init + int64/int32 detection + normalization ---------------- */

__global__ void k_init(float* deg, int* flags) {
  int i = blockIdx.x * 256 + threadIdx.x;
  if (i < NN) deg[i] = 1.0f;
  if (i < 4) flags[i] = 0;
}

/* OR sampled odd 32-bit words: all-zero across window => int64 source */
__global__ void k_detect(const unsigned* ei, const unsigned* mk,
                         const unsigned* yy, int* flags) {
  int t = threadIdx.x;
  unsigned a = 0, b = 0, c = 0;
  for (int i = t; i < 4096; i += 256) a |= ei[2 * i + 1];
  for (int i = t; i < 900;  i += 256) b |= mk[2 * i + 1];
  for (int i = t; i < 4096; i += 256) c |= yy[2 * i + 1];
  if (a) atomicOr(&flags[0], 1);
  if (b) atomicOr(&flags[1], 1);
  if (c) atomicOr(&flags[2], 1);
}

__global__ void k_cvt(const void* src, int n, const int* flags, int fi,
                      int nmax, int* dst) {
  int i = blockIdx.x * 256 + threadIdx.x;
  if (i < n) {
    int v = (flags[fi] == 0) ? (int)((const long long*)src)[i]
                             : ((const int*)src)[i];
    dst[i] = min(max(v, 0), nmax - 1);
  }
}

/* ---------------- graph prep (edge-parallel, no CSR) ---------------- */

__global__ void k_deg(const int* __restrict__ col, const float* __restrict__ w,
                      float* deg) {
  int e = blockIdx.x * 256 + threadIdx.x;
  if (e < NE) atomicAdd(&deg[col[e]], w[e]);
}

__global__ void k_dis(const float* __restrict__ deg, float* dis) {
  int i = blockIdx.x * 256 + threadIdx.x;
  if (i < NN) { float d = deg[i]; dis[i] = (d > 0.f) ? rsqrtf(d) : 0.f; }
}

__global__ void k_normv(const int* __restrict__ rows, const int* __restrict__ cols,
                        const float* __restrict__ w, const float* __restrict__ dis,
                        float* normv) {
  int e = blockIdx.x * 256 + threadIdx.x;
  if (e < NE) normv[e] = dis[rows[e]] * w[e] * dis[cols[e]];
}

/* ------------- W1 transpose + f32->bf16 (zero-padded [NPAD][KPAD]) ------------- */

__global__ void k_transW1(const float* __restrict__ W1, __bf16* __restrict__ Wt) {
  __shared__ float tile[64][65];
  int k0 = blockIdx.x * 64, n0 = blockIdx.y * 64;
  int t = threadIdx.x;
  int tn = t & 63, tk = t >> 6;
  for (int r = 0; r < 64; r += 4) {
    int k = k0 + tk + r, n = n0 + tn;
    tile[tk + r][tn] = (k < KDIM && n < H1DIM) ? W1[k * H1DIM + n] : 0.f;
  }
  __syncthreads();
  for (int r = 0; r < 64; r += 4) {
    int n = n0 + tk + r, k = k0 + tn;
    if (k < KPAD && n < NPAD)
      Wt[(size_t)n * KPAD + k] = (__bf16)tile[tn][tk + r];
  }
}

/* ------------- GEMM1: h = x(f32->bf16) @ W1, 128x256 tile, BK=32, 8 waves,
                 K split 4-way, f32 atomic accumulate into h1r ------------- */

__launch_bounds__(512)
__global__ void k_gemm1(const float* __restrict__ x, const __bf16* __restrict__ Wt,
                        float* __restrict__ hdst) {
  __shared__ __align__(16) __bf16 As[128 * 32];
  __shared__ __align__(16) __bf16 Bs[256 * 32];
  int t = threadIdx.x;
  int wv = t >> 6, lane = t & 63;
  int wm = wv >> 2, wn = wv & 3;
  int m0 = blockIdx.x * 128;
  int split = blockIdx.y;
  int kbeg = split * (KSTEPS * 32);
  int nsteps = KSTEPS + ((split == KSPL - 1) ? 1 : 0);

  f32x4 acc[4][4];
  #pragma unroll
  for (int i = 0; i < 4; ++i)
    #pragma unroll
    for (int j = 0; j < 4; ++j)
      #pragma unroll
      for (int r = 0; r < 4; ++r) acc[i][j][r] = 0.f;

  int am = t >> 2;
  int akc = (t & 3) * 8;
  long arow = m0 + am; if (arow >= NN) arow = NN - 1;
  const float* aptr = x + (size_t)arow * KDIM + akc;

  int g0 = t, g1 = t + 512;
  const __bf16* bsrc0 = Wt + (size_t)(g0 >> 2) * KPAD + (g0 & 3) * 8;
  const __bf16* bsrc1 = Wt + (size_t)(g1 >> 2) * KPAD + (g1 & 3) * 8;
  __bf16* bdst0 = Bs + (size_t)(wv * 64) * 8;
  __bf16* bdst1 = Bs + (size_t)(512 + wv * 64) * 8;

  for (int ks = 0; ks < nsteps; ++ks) {
    int k0 = kbeg + ks * 32;
    bool tail = (k0 + 32 > KDIM);
    /* A stage: f32 load -> bf16 cvt -> ds_write 16B */
    {
      bf16x8 bv;
      if (!tail || akc < 16) {
        const float4* p = (const float4*)(aptr + k0);
        float4 v0 = p[0], v1 = p[1];
        bv[0] = (__bf16)v0.x; bv[1] = (__bf16)v0.y;
        bv[2] = (__bf16)v0.z; bv[3] = (__bf16)v0.w;
        bv[4] = (__bf16)v1.x; bv[5] = (__bf16)v1.y;
        bv[6] = (__bf16)v1.z; bv[7] = (__bf16)v1.w;
      } else {
        #pragma unroll
        for (int q = 0; q < 8; ++q) bv[q] = (__bf16)0.f;
      }
      *(bf16x8*)&As[am * 32 + akc] = bv;
    }
    /* B stage: async global->LDS, Wt is zero-padded past K=10000 */
    load_lds16(bsrc0 + k0, bdst0);
    load_lds16(bsrc1 + k0, bdst1);
    __syncthreads();

    bf16x8 af[4], bf[4];
    int lrow = lane & 15, lk = (lane >> 4) * 8;
    #pragma unroll
    for (int i = 0; i < 4; ++i)
      af[i] = *(const bf16x8*)&As[(wm * 64 + i * 16 + lrow) * 32 + lk];
    #pragma unroll
    for (int j = 0; j < 4; ++j)
      bf[j] = *(const bf16x8*)&Bs[(wn * 64 + j * 16 + lrow) * 32 + lk];
    #pragma unroll
    for (int i = 0; i < 4; ++i)
      #pragma unroll
      for (int j = 0; j < 4; ++j)
        acc[i][j] = __builtin_amdgcn_mfma_f32_16x16x32_bf16(af[i], bf[j], acc[i][j], 0, 0, 0);
    __syncthreads();
  }

  int colb = wn * 64 + (lane & 15);
  int rbase = m0 + wm * 64 + ((lane >> 4) * 4);
  #pragma unroll
  for (int i = 0; i < 4; ++i)
    #pragma unroll
    for (int j = 0; j < 4; ++j) {
      int cg = colb + j * 16;
      #pragma unroll
      for (int r = 0; r < 4; ++r) {
        int rg = rbase + i * 16 + r;
        if (rg < NN) atomicAdd(&hdst[(size_t)rg * NPAD + cg], acc[i][j][r]);
      }
    }
}

__global__ void k_zero(float* p, int n4) {
  int i = blockIdx.x * 256 + threadIdx.x;
  if (i < n4) { f32x4 z; z[0]=0;z[1]=0;z[2]=0;z[3]=0; ((f32x4*)p)[i] = z; }
}

/* ------------- aggregation 1: edge-parallel atomics (ch = feature chunk of 8) ------------- */

__global__ void k_agg1e(const float* __restrict__ h1r, const float* __restrict__ normv,
                        const int* __restrict__ rows, const int* __restrict__ cols,
                        float* hacc) {
  int idx = blockIdx.x * 256 + threadIdx.x;     /* idx = ch*NE + e, ch in [0,25) */
  if (idx < 25 * NE) {
    int ch = idx / NE;
    int e  = idx - ch * NE;
    float nv = normv[e];
    const float* src = h1r + (size_t)rows[e] * NPAD + ch * 8;
    float*       dst = hacc + (size_t)cols[e] * NPAD + ch * 8;
    #pragma unroll
    for (int q = 0; q < 8; ++q) atomicAdd(&dst[q], nv * src[q]);
  }
}

/* finalize layer 1 in place: hacc = relu(hacc + dis^2 * h1r + b1) */
__global__ void k_fin1(float* hacc, const float* __restrict__ h1r,
                       const float* __restrict__ dis, const float* __restrict__ b1) {
  int c = blockIdx.x, t = threadIdx.x;
  if (t < H1DIM) {
    float d = dis[c];
    float v = hacc[(size_t)c * NPAD + t] + d * d * h1r[(size_t)c * NPAD + t] + b1[t];
    hacc[(size_t)c * NPAD + t] = fmaxf(v, 0.f);
  }
}

/* ------------- layer-2 linear, aggregation 2 (edge-parallel), output gather ------------- */

__global__ void k_lin2(const float* __restrict__ h1a, const float* __restrict__ W2,
                       float* __restrict__ h2) {
  int i = blockIdx.x * 256 + threadIdx.x;
  if (i < NN * NCLS) {
    int c = i >> 3, o = i & 7;
    const float* hr = h1a + (size_t)c * NPAD;
    float acc = 0.f;
    #pragma unroll 4
    for (int k = 0; k < H1DIM; ++k) acc += hr[k] * W2[k * NCLS + o];
    h2[i] = acc;
  }
}

__global__ void k_agg2e(const float* __restrict__ h2, const float* __restrict__ normv,
                        const int* __restrict__ rows, const int* __restrict__ cols,
                        float* acc2) {
  int e = blockIdx.x * 256 + threadIdx.x;
  if (e < NE) {
    float nv = normv[e];
    const float* src = h2 + (size_t)rows[e] * NCLS;
    float*       dst = acc2 + (size_t)cols[e] * NCLS;
    #pragma unroll
    for (int o = 0; o < NCLS; ++o) atomicAdd(&dst[o], nv * src[o]);
  }
}

/* finalize layer 2 in place: acc2 = acc2 + dis^2 * h2 + b2 */
__global__ void k_fin2(float* acc2, const float* __restrict__ h2,
                       const float* __restrict__ dis, const float* __restrict__ b2) {
  int i = blockIdx.x * 256 + threadIdx.x;
  if (i < NN * NCLS) {
    int c = i >> 3, o = i & 7;
    float d = dis[c];
    acc2[i] = acc2[i] + d * d * h2[i] + b2[o];
  }
}

/* ------------- output gather: FLOAT32 out (predictions, then targets) ------------- */

__global__ void k_out(const float* __restrict__ out2, const int* __restrict__ mask,
                      const int* __restrict__ yv, float* __restrict__ out) {
  int i = blockIdx.x * 256 + threadIdx.x;
  if (i < NTST * NCLS) {
    int r = i >> 3, o = i & 7;
    out[i] = out2[(size_t)mask[r] * NCLS + o];
  } else if (i < NTST * NCLS + NTST) {
    int r = i - NTST * NCLS;
    out[i] = (float)yv[mask[r]];
  }
}

/* ---------------- host ---------------- */

extern "C" void kernel_launch(void* const* d_in, const int* in_sizes, int n_in,
                              void* d_out, int out_size, void* d_ws, size_t ws_size,
                              hipStream_t stream) {
  const float* x    = (const float*)d_in[0];
  const void*  ei   = d_in[1];
  const float* ew   = (const float*)d_in[2];
  const void*  mask = d_in[3];
  const void*  y    = d_in[4];
  const float* W1   = (const float*)d_in[5];
  const float* b1   = (const float*)d_in[6];
  const float* W2   = (const float*)d_in[7];
  const float* b2   = (const float*)d_in[8];
  float* out = (float*)d_out;

  char* ws = (char*)d_ws;
  float* deg    = (float*)(ws + 0);                         /* 40 KB   */
  float* dis    = (float*)(ws + (64 << 10));                /* 40 KB   */
  float* normv  = (float*)(ws + (128 << 10));               /* 1.28 MB */
  int*   idx32  = (int*)(ws + (2 << 20));                   /* 2.56 MB */
  float* h2     = (float*)(ws + (5 << 20));                 /* 320 KB  */
  float* acc2   = (float*)(ws + (5 << 20) + (512 << 10));   /* 320 KB  */
  int*   mask32 = (int*)(ws + (6 << 20));                   /* 8 KB    */
  int*   y32    = (int*)(ws + (6 << 20) + (64 << 10));      /* 40 KB   */
  int*   flags  = (int*)(ws + (6 << 20) + (128 << 10));     /* 16 B    */
  __bf16* Wt    = (__bf16*)(ws + ((size_t)8 << 20));        /* 4.89 MB */
  float* h1r    = (float*)(ws + ((size_t)16 << 20));        /* 10.24 MB*/
  float* hacc   = (float*)(ws + ((size_t)27 << 20));        /* 10.24 MB, ends ~36.8 MB */

  int* rows32 = idx32;
  int* cols32 = idx32 + NE;

  k_init<<<dim3(40), dim3(256), 0, stream>>>(deg, flags);
  k_detect<<<dim3(1), dim3(256), 0, stream>>>((const unsigned*)ei, (const unsigned*)mask,
                                              (const unsigned*)y, flags);
  k_cvt<<<dim3(2500), dim3(256), 0, stream>>>(ei, 2 * NE, flags, 0, NN, idx32);
  k_cvt<<<dim3(8),    dim3(256), 0, stream>>>(mask, NTST, flags, 1, NN, mask32);
  k_cvt<<<dim3(40),   dim3(256), 0, stream>>>(y, NN, flags, 2, NN, y32);

  k_deg<<<dim3(1250), dim3(256), 0, stream>>>(cols32, ew, deg);
  k_dis<<<dim3(40), dim3(256), 0, stream>>>(deg, dis);
  k_normv<<<dim3(1250), dim3(256), 0, stream>>>(rows32, cols32, ew, dis, normv);
  k_transW1<<<dim3(157, 4), dim3(256), 0, stream>>>(W1, Wt);

  k_zero<<<dim3(2500), dim3(256), 0, stream>>>(h1r, NN * NPAD / 4);
  k_zero<<<dim3(2500), dim3(256), 0, stream>>>(hacc, NN * NPAD / 4);
  k_zero<<<dim3(79),   dim3(256), 0, stream>>>(acc2, NN * NCLS / 4);

  k_gemm1<<<dim3(79, KSPL), dim3(512), 0, stream>>>(x, Wt, h1r);

  k_agg1e<<<dim3((25 * NE + 255) / 256), dim3(256), 0, stream>>>(h1r, normv, rows32, cols32, hacc);
  k_fin1<<<dim3(10000), dim3(256), 0, stream>>>(hacc, h1r, dis, b1);

  k_lin2<<<dim3(313), dim3(256), 0, stream>>>(hacc, W2, h2);
  k_agg2e<<<dim3(1250), dim3(256), 0, stream>>>(h2, normv, rows32, cols32, acc2);
  k_fin2<<<dim3(313), dim3(256), 0, stream>>>(acc2, h2, dis, b2);
  k_out<<<dim3(71), dim3(256), 0, stream>>>(acc2, mask32, y32, out);
}

// Round 5
// 379.894 us; speedup vs baseline: 9.5329x; 9.5329x over previous
//
#include <hip/hip_runtime.h>
#include <hip/hip_bf16.h>

#define NN     10000
#define NE     320000
#define H1DIM  200
#define NPAD   256
#define NCLS   8
#define NTST   2000
#define KDIM   10000
#define KPAD   10016
#define KSPL   4
#define KSTEPS 78   /* 78*32*4 = 9984, +16 tail on split 3 */

typedef __bf16 bf16x8 __attribute__((ext_vector_type(8)));
typedef float  f32x4  __attribute__((ext_vector_type(4)));

__device__ __forceinline__ void load_lds16(const void* g, void* l) {
  __builtin_amdgcn_global_load_lds(
      (__attribute__((address_space(1))) void*)(void*)g,
      (__attribute__((address_space(3))) void*)l, 16, 0, 0);
}

/* ---------------- init + int64/int32 detection + normalization ---------------- */

__global__ void k_init(float* deg, int* cnt, int* cur, int* flags) {
  int i = blockIdx.x * 256 + threadIdx.x;
  if (i < NN) { deg[i] = 1.0f; cnt[i] = 0; cur[i] = 0; }
  if (i < 4) flags[i] = 0;
}

/* OR sampled odd 32-bit words: all-zero across window => int64 source */
__global__ void k_detect(const unsigned* ei, const unsigned* mk,
                         const unsigned* yy, int* flags) {
  int t = threadIdx.x;
  unsigned a = 0, b = 0, c = 0;
  for (int i = t; i < 4096; i += 256) a |= ei[2 * i + 1];
  for (int i = t; i < 900;  i += 256) b |= mk[2 * i + 1];
  for (int i = t; i < 4096; i += 256) c |= yy[2 * i + 1];
  if (a) atomicOr(&flags[0], 1);
  if (b) atomicOr(&flags[1], 1);
  if (c) atomicOr(&flags[2], 1);
}

__global__ void k_cvt(const void* src, int n, const int* flags, int fi,
                      int nmax, int* dst) {
  int i = blockIdx.x * 256 + threadIdx.x;
  if (i < n) {
    int v = (flags[fi] == 0) ? (int)((const long long*)src)[i]
                             : ((const int*)src)[i];
    dst[i] = min(max(v, 0), nmax - 1);
  }
}

/* ---------------- graph prep: degree + CSR by target node ---------------- */

__global__ void k_deg(const int* __restrict__ col, const float* __restrict__ w,
                      float* deg, int* cnt) {
  int e = blockIdx.x * 256 + threadIdx.x;
  if (e < NE) {
    int c = col[e];
    atomicAdd(&deg[c], w[e]);
    atomicAdd(&cnt[c], 1);
  }
}

__global__ void k_dis(const float* __restrict__ deg, float* dis) {
  int i = blockIdx.x * 256 + threadIdx.x;
  if (i < NN) { float d = deg[i]; dis[i] = (d > 0.f) ? rsqrtf(d) : 0.f; }
}

/* exclusive prefix sum of cnt -> rowptr (single block, 1024 thr, 16 waves) */
__global__ void k_scan(const int* __restrict__ cnt, int* rowptr) {
  __shared__ int wsum[16];
  __shared__ int carry;
  int t = threadIdx.x;
  int lane = t & 63, wid = t >> 6;
  if (t == 0) carry = 0;
  __syncthreads();
  for (int base = 0; base < NN; base += 1024) {
    int idx = base + t;
    int v = (idx < NN) ? cnt[idx] : 0;
    int x = v;
    #pragma unroll
    for (int off = 1; off < 64; off <<= 1) {
      int y = __shfl_up(x, off);
      if (lane >= off) x += y;
    }
    if (lane == 63) wsum[wid] = x;
    __syncthreads();
    int c0 = carry;
    if (t < 16) {
      int s = wsum[t];
      #pragma unroll
      for (int off = 1; off < 16; off <<= 1) {
        int y = __shfl_up(s, off);
        if (t >= off) s += y;
      }
      wsum[t] = s;
    }
    __syncthreads();
    int woff = (wid == 0) ? 0 : wsum[wid - 1];
    if (idx < NN) rowptr[idx] = c0 + woff + x - v;
    int tot = wsum[15];
    __syncthreads();
    if (t == 0) carry = c0 + tot;
    __syncthreads();
  }
  if (t == 0) rowptr[NN] = carry;
}

__global__ void k_norm_scatter(const int* __restrict__ rows, const int* __restrict__ cols,
                               const float* __restrict__ w, const float* __restrict__ dis,
                               const int* __restrict__ rowptr, int* cur,
                               float* normv, int* eids) {
  int e = blockIdx.x * 256 + threadIdx.x;
  if (e < NE) {
    int r = rows[e], c = cols[e];
    normv[e] = dis[r] * w[e] * dis[c];
    int pos = rowptr[c] + atomicAdd(&cur[c], 1);
    eids[pos] = e;
  }
}

/* ------------- W1 transpose + f32->bf16 (zero-padded [NPAD][KPAD]) ------------- */

__global__ void k_transW1(const float* __restrict__ W1, __bf16* __restrict__ Wt) {
  __shared__ float tile[64][65];
  int k0 = blockIdx.x * 64, n0 = blockIdx.y * 64;
  int t = threadIdx.x;
  int tn = t & 63, tk = t >> 6;
  for (int r = 0; r < 64; r += 4) {
    int k = k0 + tk + r, n = n0 + tn;
    tile[tk + r][tn] = (k < KDIM && n < H1DIM) ? W1[k * H1DIM + n] : 0.f;
  }
  __syncthreads();
  for (int r = 0; r < 64; r += 4) {
    int n = n0 + tk + r, k = k0 + tn;
    if (k < KPAD && n < NPAD)
      Wt[(size_t)n * KPAD + k] = (__bf16)tile[tn][tk + r];
  }
}

/* ------------- GEMM1: h = x(f32->bf16) @ W1, 128x256 tile, BK=32, 8 waves,
                 K split 4-way, f32 atomic accumulate into h1r ------------- */

__launch_bounds__(512)
__global__ void k_gemm1(const float* __restrict__ x, const __bf16* __restrict__ Wt,
                        float* __restrict__ hdst) {
  __shared__ __align__(16) __bf16 As[128 * 32];
  __shared__ __align__(16) __bf16 Bs[256 * 32];
  int t = threadIdx.x;
  int wv = t >> 6, lane = t & 63;
  int wm = wv >> 2, wn = wv & 3;
  int m0 = blockIdx.x * 128;
  int split = blockIdx.y;
  int kbeg = split * (KSTEPS * 32);
  int nsteps = KSTEPS + ((split == KSPL - 1) ? 1 : 0);

  f32x4 acc[4][4];
  #pragma unroll
  for (int i = 0; i < 4; ++i)
    #pragma unroll
    for (int j = 0; j < 4; ++j)
      #pragma unroll
      for (int r = 0; r < 4; ++r) acc[i][j][r] = 0.f;

  int am = t >> 2;
  int akc = (t & 3) * 8;
  long arow = m0 + am; if (arow >= NN) arow = NN - 1;
  const float* aptr = x + (size_t)arow * KDIM + akc;

  int g0 = t, g1 = t + 512;
  const __bf16* bsrc0 = Wt + (size_t)(g0 >> 2) * KPAD + (g0 & 3) * 8;
  const __bf16* bsrc1 = Wt + (size_t)(g1 >> 2) * KPAD + (g1 & 3) * 8;
  __bf16* bdst0 = Bs + (size_t)(wv * 64) * 8;
  __bf16* bdst1 = Bs + (size_t)(512 + wv * 64) * 8;

  for (int ks = 0; ks < nsteps; ++ks) {
    int k0 = kbeg + ks * 32;
    bool tail = (k0 + 32 > KDIM);
    /* A stage: f32 load -> bf16 cvt -> ds_write 16B */
    {
      bf16x8 bv;
      if (!tail || akc < 16) {
        const float4* p = (const float4*)(aptr + k0);
        float4 v0 = p[0], v1 = p[1];
        bv[0] = (__bf16)v0.x; bv[1] = (__bf16)v0.y;
        bv[2] = (__bf16)v0.z; bv[3] = (__bf16)v0.w;
        bv[4] = (__bf16)v1.x; bv[5] = (__bf16)v1.y;
        bv[6] = (__bf16)v1.z; bv[7] = (__bf16)v1.w;
      } else {
        #pragma unroll
        for (int q = 0; q < 8; ++q) bv[q] = (__bf16)0.f;
      }
      *(bf16x8*)&As[am * 32 + akc] = bv;
    }
    /* B stage: async global->LDS, Wt is zero-padded past K=10000 */
    load_lds16(bsrc0 + k0, bdst0);
    load_lds16(bsrc1 + k0, bdst1);
    __syncthreads();

    bf16x8 af[4], bf[4];
    int lrow = lane & 15, lk = (lane >> 4) * 8;
    #pragma unroll
    for (int i = 0; i < 4; ++i)
      af[i] = *(const bf16x8*)&As[(wm * 64 + i * 16 + lrow) * 32 + lk];
    #pragma unroll
    for (int j = 0; j < 4; ++j)
      bf[j] = *(const bf16x8*)&Bs[(wn * 64 + j * 16 + lrow) * 32 + lk];
    #pragma unroll
    for (int i = 0; i < 4; ++i)
      #pragma unroll
      for (int j = 0; j < 4; ++j)
        acc[i][j] = __builtin_amdgcn_mfma_f32_16x16x32_bf16(af[i], bf[j], acc[i][j], 0, 0, 0);
    __syncthreads();
  }

  int colb = wn * 64 + (lane & 15);
  int rbase = m0 + wm * 64 + ((lane >> 4) * 4);
  #pragma unroll
  for (int i = 0; i < 4; ++i)
    #pragma unroll
    for (int j = 0; j < 4; ++j) {
      int cg = colb + j * 16;
      #pragma unroll
      for (int r = 0; r < 4; ++r) {
        int rg = rbase + i * 16 + r;
        if (rg < NN) atomicAdd(&hdst[(size_t)rg * NPAD + cg], acc[i][j][r]);
      }
    }
}

__global__ void k_zero(float* p, int n4) {
  int i = blockIdx.x * 256 + threadIdx.x;
  if (i < n4) { f32x4 z; z[0]=0;z[1]=0;z[2]=0;z[3]=0; ((f32x4*)p)[i] = z; }
}

/* ------------- aggregation 1: CSR gather, block per node, fused bias+relu ------------- */

__global__ void k_agg1(const float* __restrict__ h1r, const float* __restrict__ dis,
                       const float* __restrict__ normv, const int* __restrict__ rows,
                       const int* __restrict__ rowptr, const int* __restrict__ eids,
                       const float* __restrict__ b1, float* __restrict__ h1a) {
  __shared__ int   s_r[512];
  __shared__ float s_n[512];
  int c = blockIdx.x;
  int t = threadIdx.x;
  int p0 = rowptr[c], len = rowptr[c + 1] - p0;
  float acc = 0.f;
  for (int base = 0; base < len; base += 512) {
    int chunk = min(512, len - base);
    for (int j = t; j < chunk; j += 256) {
      int e = eids[p0 + base + j];
      s_r[j] = rows[e];
      s_n[j] = normv[e];
    }
    __syncthreads();
    if (t < H1DIM) {
      int j = 0;
      for (; j + 4 <= chunk; j += 4) {
        float v0 = s_n[j + 0] * h1r[(size_t)s_r[j + 0] * NPAD + t];
        float v1 = s_n[j + 1] * h1r[(size_t)s_r[j + 1] * NPAD + t];
        float v2 = s_n[j + 2] * h1r[(size_t)s_r[j + 2] * NPAD + t];
        float v3 = s_n[j + 3] * h1r[(size_t)s_r[j + 3] * NPAD + t];
        acc += v0 + v1 + v2 + v3;
      }
      for (; j < chunk; ++j) acc += s_n[j] * h1r[(size_t)s_r[j] * NPAD + t];
    }
    __syncthreads();
  }
  if (t < H1DIM) {
    float d = dis[c];
    acc += d * d * h1r[(size_t)c * NPAD + t] + b1[t];
    h1a[(size_t)c * NPAD + t] = fmaxf(acc, 0.f);
  }
}

/* ------------- layer-2 linear, aggregation 2 (CSR, fused finalize), output ------------- */

__global__ void k_lin2(const float* __restrict__ h1a, const float* __restrict__ W2,
                       float* __restrict__ h2) {
  int i = blockIdx.x * 256 + threadIdx.x;
  if (i < NN * NCLS) {
    int c = i >> 3, o = i & 7;
    const float* hr = h1a + (size_t)c * NPAD;
    float acc = 0.f;
    #pragma unroll 4
    for (int k = 0; k < H1DIM; ++k) acc += hr[k] * W2[k * NCLS + o];
    h2[i] = acc;
  }
}

__global__ void k_agg2(const float* __restrict__ h2, const float* __restrict__ dis,
                       const float* __restrict__ normv, const int* __restrict__ rows,
                       const int* __restrict__ rowptr, const int* __restrict__ eids,
                       const float* __restrict__ b2, float* __restrict__ out2) {
  int i = blockIdx.x * 256 + threadIdx.x;
  if (i < NN * NCLS) {
    int c = i >> 3, o = i & 7;
    float d = dis[c];
    float acc = d * d * h2[i];
    int p0 = rowptr[c], p1 = rowptr[c + 1];
    for (int j = p0; j < p1; ++j) {
      int e = eids[j];
      acc += normv[e] * h2[rows[e] * NCLS + o];
    }
    out2[i] = acc + b2[o];
  }
}

/* ------------- output gather: FLOAT32 out (predictions, then targets) ------------- */

__global__ void k_out(const float* __restrict__ out2, const int* __restrict__ mask,
                      const int* __restrict__ yv, float* __restrict__ out) {
  int i = blockIdx.x * 256 + threadIdx.x;
  if (i < NTST * NCLS) {
    int r = i >> 3, o = i & 7;
    out[i] = out2[(size_t)mask[r] * NCLS + o];
  } else if (i < NTST * NCLS + NTST) {
    int r = i - NTST * NCLS;
    out[i] = (float)yv[mask[r]];
  }
}

/* ---------------- host ---------------- */

extern "C" void kernel_launch(void* const* d_in, const int* in_sizes, int n_in,
                              void* d_out, int out_size, void* d_ws, size_t ws_size,
                              hipStream_t stream) {
  const float* x    = (const float*)d_in[0];
  const void*  ei   = d_in[1];
  const float* ew   = (const float*)d_in[2];
  const void*  mask = d_in[3];
  const void*  y    = d_in[4];
  const float* W1   = (const float*)d_in[5];
  const float* b1   = (const float*)d_in[6];
  const float* W2   = (const float*)d_in[7];
  const float* b2   = (const float*)d_in[8];
  float* out = (float*)d_out;

  char* ws = (char*)d_ws;
  float* deg    = (float*)(ws + 0);                         /* 40 KB   */
  float* dis    = (float*)(ws + (64 << 10));                /* 40 KB   */
  float* normv  = (float*)(ws + (128 << 10));               /* 1.28 MB */
  int*   idx32  = (int*)(ws + (2 << 20));                   /* 2.56 MB */
  float* h2     = (float*)(ws + (5 << 20));                 /* 320 KB  */
  float* out2   = (float*)(ws + (5 << 20) + (512 << 10));   /* 320 KB  */
  int*   mask32 = (int*)(ws + (6 << 20));                   /* 8 KB    */
  int*   y32    = (int*)(ws + (6 << 20) + (64 << 10));      /* 40 KB   */
  int*   flags  = (int*)(ws + (6 << 20) + (128 << 10));     /* 16 B    */
  int*   cnt    = (int*)(ws + (6 << 20) + (256 << 10));     /* 40 KB   */
  int*   cur    = (int*)(ws + (6 << 20) + (384 << 10));     /* 40 KB   */
  int*   rowptr = (int*)(ws + (6 << 20) + (512 << 10));     /* 40 KB   */
  int*   eids   = (int*)(ws + (7 << 20));                   /* 1.28 MB */
  __bf16* Wt    = (__bf16*)(ws + ((size_t)9 << 20));        /* 4.89 MB */
  float* h1r    = (float*)(ws + ((size_t)16 << 20));        /* 10.24 MB*/
  float* h1a    = (float*)(ws + ((size_t)27 << 20));        /* 10.24 MB, ends ~36.8 MB */

  int* rows32 = idx32;
  int* cols32 = idx32 + NE;

  k_init<<<dim3(40), dim3(256), 0, stream>>>(deg, cnt, cur, flags);
  k_detect<<<dim3(1), dim3(256), 0, stream>>>((const unsigned*)ei, (const unsigned*)mask,
                                              (const unsigned*)y, flags);
  k_cvt<<<dim3(2500), dim3(256), 0, stream>>>(ei, 2 * NE, flags, 0, NN, idx32);
  k_cvt<<<dim3(8),    dim3(256), 0, stream>>>(mask, NTST, flags, 1, NN, mask32);
  k_cvt<<<dim3(40),   dim3(256), 0, stream>>>(y, NN, flags, 2, NN, y32);

  k_deg<<<dim3(1250), dim3(256), 0, stream>>>(cols32, ew, deg, cnt);
  k_dis<<<dim3(40), dim3(256), 0, stream>>>(deg, dis);
  k_scan<<<dim3(1), dim3(1024), 0, stream>>>(cnt, rowptr);
  k_norm_scatter<<<dim3(1250), dim3(256), 0, stream>>>(rows32, cols32, ew, dis, rowptr, cur, normv, eids);
  k_transW1<<<dim3(157, 4), dim3(256), 0, stream>>>(W1, Wt);

  k_zero<<<dim3(2500), dim3(256), 0, stream>>>(h1r, NN * NPAD / 4);
  k_gemm1<<<dim3(79, KSPL), dim3(512), 0, stream>>>(x, Wt, h1r);

  k_agg1<<<dim3(10000), dim3(256), 0, stream>>>(h1r, dis, normv, rows32, rowptr, eids, b1, h1a);
  k_lin2<<<dim3(313), dim3(256), 0, stream>>>(h1a, W2, h2);
  k_agg2<<<dim3(313), dim3(256), 0, stream>>>(h2, dis, normv, rows32, rowptr, eids, b2, out2);
  k_out<<<dim3(71), dim3(256), 0, stream>>>(out2, mask32, y32, out);
}